// Round 11
// baseline (223.418 us; speedup 1.0000x reference)
//
#include <hip/hip_runtime.h>
#include <hip/hip_bf16.h>
#include <cstddef>
#include <cstdint>

#define NROWS 8192
#define LOG2E 1.4426950408889634f

typedef __attribute__((ext_vector_type(8))) short bf16x8;
typedef __attribute__((ext_vector_type(4))) float f32x4;

#define EXP2(x) __builtin_amdgcn_exp2f(x)

__device__ __forceinline__ short f2bf(float f) {
  unsigned u = __float_as_uint(f);
  u += 0x7fffu + ((u >> 16) & 1u);   // RNE
  return (short)(u >> 16);
}
__device__ __forceinline__ float leaky_f(float v) { return fmaxf(v, 0.1f * v); }

union BFPair { __hip_bfloat162 h; unsigned u; };
__device__ __forceinline__ unsigned pack2(float a, float b) {
  BFPair p;
  p.h = __float22bfloat162_rn(make_float2(a, b));  // v_cvt_pk_bf16_f32
  return p.u;
}
__device__ __forceinline__ f32x4 ntload4(const float* p) {
  return __builtin_nontemporal_load((const f32x4*)p);
}

// ---------------- Kernel 1: MLP encoder: x[8192,256] -> x2, s(prescaled), sq, x2bfT --
extern "C" __global__ void __launch_bounds__(256)
encoder_kernel(const float* __restrict__ x, const float* __restrict__ W10,
               const float* __restrict__ b10, const float* __restrict__ W11,
               const float* __restrict__ b11, const float* __restrict__ avec,
               float* __restrict__ x2, float* __restrict__ sarr,
               float* __restrict__ sqarr, short* __restrict__ x2bfT) {
  __shared__ float xr[4][256];
  __shared__ float h1[4][128];
  const int t = threadIdx.x;
  const int r0 = blockIdx.x * 4;
#pragma unroll
  for (int r = 0; r < 4; ++r) xr[r][t] = x[(size_t)(r0 + r) * 256 + t];
  __syncthreads();
  if (t < 128) {
    float acc[4];
    const float b = b10[t];
#pragma unroll
    for (int r = 0; r < 4; ++r) acc[r] = b;
    const float* wrow = W10 + t * 256;
    for (int c = 0; c < 256; c += 4) {
      const float4 wv = *(const float4*)(wrow + c);
#pragma unroll
      for (int r = 0; r < 4; ++r) {
        acc[r] = fmaf(wv.x, xr[r][c], acc[r]);
        acc[r] = fmaf(wv.y, xr[r][c + 1], acc[r]);
        acc[r] = fmaf(wv.z, xr[r][c + 2], acc[r]);
        acc[r] = fmaf(wv.w, xr[r][c + 3], acc[r]);
      }
    }
#pragma unroll
    for (int r = 0; r < 4; ++r) h1[r][t] = leaky_f(acc[r]);
  }
  __syncthreads();
  if (t < 64) {
    float acc[4];
    const float b = b11[t];
#pragma unroll
    for (int r = 0; r < 4; ++r) acc[r] = b;
    const float* wrow = W11 + t * 128;
    for (int c = 0; c < 128; c += 4) {
      const float4 wv = *(const float4*)(wrow + c);
#pragma unroll
      for (int r = 0; r < 4; ++r) {
        acc[r] = fmaf(wv.x, h1[r][c], acc[r]);
        acc[r] = fmaf(wv.y, h1[r][c + 1], acc[r]);
        acc[r] = fmaf(wv.z, h1[r][c + 2], acc[r]);
        acc[r] = fmaf(wv.w, h1[r][c + 3], acc[r]);
      }
    }
    const float av = avec[t];
#pragma unroll
    for (int r = 0; r < 4; ++r) {
      const float v = leaky_f(acc[r]);
      x2[(size_t)(r0 + r) * 64 + t] = v;
      x2bfT[(size_t)t * NROWS + r0 + r] = f2bf(v);
      float ps = v * av, pq = v * v;
#pragma unroll
      for (int off = 1; off < 64; off <<= 1) {
        ps += __shfl_xor(ps, off);
        pq += __shfl_xor(pq, off);
      }
      if (t == 0) {
        sarr[r0 + r] = ps * LOG2E;          // exp(leaky(d)) = exp2(leaky(d*log2e))
        sqarr[r0 + r] = pq * (1.0f / 64.0f);
      }
    }
  }
}

// ---------------- Kernel 1b: B fragments (16x16x32 layout, contiguous) --------------
// Bfrag[S][nf][lane][8]: x2^T[n = nf*16 + (lane&15)][k = S*32 + (lane>>4)*8 + e]
extern "C" __global__ void __launch_bounds__(256)
prep16_kernel(const short* __restrict__ x2bfT, short* __restrict__ Bfrag) {
  const int S = blockIdx.x;           // 256 k-groups of 32
  const int t = threadIdx.x;
  const int nf = t >> 6, l = t & 63;
  const bf16x8 v = *(const bf16x8*)(x2bfT + (size_t)(nf * 16 + (l & 15)) * NROWS
                                    + S * 32 + (l >> 4) * 8);
  *(bf16x8*)(Bfrag + ((size_t)S * 4 + nf) * 512 + l * 8) = v;
}

// ---------------- Kernel 2: DENSE-WAVEFRONT convert pass (the only A reader) --------
// Pure grid-stride sweep in flat address order (m13/fillBuffer pattern): wave gw
// handles 1KB chunks {gw + k*8192}. Per chunk: 1KB contiguous nt-read of A, exp2,
// 512B contiguous bf16 write of raw (row-major), exact fp32 chunk partials to fixed
// slots (wave shfl reduce; no atomics -> deterministic).
extern "C" __global__ void __launch_bounds__(256)
convert_kernel(const float* __restrict__ A, const float* __restrict__ sarr,
               const float* __restrict__ sqarr, short* __restrict__ raw,
               float* __restrict__ rspc, float* __restrict__ sspc,
               float* __restrict__ wspc) {
  const int t = threadIdx.x, l = t & 63, w = t >> 6;
  const int gw = blockIdx.x * 4 + w;          // 0..8191
#pragma unroll 1
  for (int k = 0; k < 32; ++k) {
    const int chunk = gw + k * 8192;          // 0..262143, chip sweeps in order
    const int i = chunk >> 5;                 // row (uniform per wave)
    const int jc = (chunk & 31) << 8;         // column base of this 256-elem chunk
    const float sif = sarr[i];
    const f32x4 a4 = ntload4(A + (size_t)chunk * 256 + l * 4);
    const f32x4 sj = *(const f32x4*)(sarr + jc + l * 4);
    const f32x4 sq = *(const f32x4*)(sqarr + jc + l * 4);
    const float d0 = sif - sj[0], d1 = sif - sj[1];
    const float d2 = sif - sj[2], d3 = sif - sj[3];
    const float r0 = EXP2(fmaxf(d0, 0.1f * d0)) * a4[0];
    const float r1 = EXP2(fmaxf(d1, 0.1f * d1)) * a4[1];
    const float r2 = EXP2(fmaxf(d2, 0.1f * d2)) * a4[2];
    const float r3 = EXP2(fmaxf(d3, 0.1f * d3)) * a4[3];
    uint2 pk;
    pk.x = pack2(r0, r1);
    pk.y = pack2(r2, r3);
    *(uint2*)(raw + (size_t)chunk * 256 + l * 4) = pk;   // 512B/wave contiguous
    float a = (r0 + r1) + (r2 + r3);
    float b = fmaf(r0, r0, fmaf(r1, r1, fmaf(r2, r2, r3 * r3)));
    float c = fmaf(r0, sq[0], fmaf(r1, sq[1], fmaf(r2, sq[2], r3 * sq[3])));
#pragma unroll
    for (int off = 1; off < 64; off <<= 1) {
      a += __shfl_xor(a, off);
      b += __shfl_xor(b, off);
      c += __shfl_xor(c, off);
    }
    if (l == 0) { rspc[chunk] = a; sspc[chunk] = b; wspc[chunk] = c; }
  }
}

// ---------------- Kernel 2b: fold 32 chunk-partials per row into exact scalars ------
extern "C" __global__ void __launch_bounds__(256)
rowreduce_kernel(const float* __restrict__ rspc, const float* __restrict__ sspc,
                 const float* __restrict__ wspc, float* __restrict__ rs,
                 float* __restrict__ ss, float* __restrict__ ws) {
  const int i = blockIdx.x * 256 + threadIdx.x;   // 8192 rows
  float a = 0.f, b = 0.f, c = 0.f;
#pragma unroll
  for (int q = 0; q < 32; ++q) {
    a += rspc[i * 32 + q];
    b += sspc[i * 32 + q];
    c += wspc[i * 32 + q];
  }
  rs[i] = a; ss[i] = b; ws[i] = c;
}

// ---------------- Kernel 3: tiled MFMA GEMM over L3-resident raw --------------------
// Block = (rt-pair, kp quarter); wave w: 16 S-tiles x {2 A-frag scatter reads (L3),
// 4KB L2-hot Bfrag, 8 MFMA}. Partial p = kp*4+w (16 partials), combined in finish.
extern "C" __global__ void __launch_bounds__(256)
gemm_kernel(const short* __restrict__ raw, const short* __restrict__ Bfrag,
            float* __restrict__ yp) {
  const int t = threadIdx.x, l = t & 63, w = t >> 6;
  const int rtp = blockIdx.x >> 2;        // 0..255 (32-row groups)
  const int kp = blockIdx.x & 3;
  const int S0 = kp * 64 + w * 16;
  const int row0 = rtp * 32;
  const short* a0 = raw + (size_t)(row0 + (l & 15)) * NROWS + S0 * 32 + (l >> 4) * 8;
  const short* a1 = a0 + (size_t)16 * NROWS;
  const short* bp = Bfrag + (size_t)S0 * 2048 + l * 8;

  f32x4 acc0[4], acc1[4];
#pragma unroll
  for (int nf = 0; nf < 4; ++nf) {
    acc0[nf] = (f32x4){0.f, 0.f, 0.f, 0.f};
    acc1[nf] = (f32x4){0.f, 0.f, 0.f, 0.f};
  }
#pragma unroll
  for (int s = 0; s < 16; ++s) {
    const bf16x8 ar0 = *(const bf16x8*)(a0 + s * 32);
    const bf16x8 ar1 = *(const bf16x8*)(a1 + s * 32);
    const short* bs = bp + (size_t)s * 2048;
    const bf16x8 b0 = *(const bf16x8*)(bs);
    const bf16x8 b1 = *(const bf16x8*)(bs + 512);
    const bf16x8 b2 = *(const bf16x8*)(bs + 1024);
    const bf16x8 b3 = *(const bf16x8*)(bs + 1536);
    acc0[0] = __builtin_amdgcn_mfma_f32_16x16x32_bf16(ar0, b0, acc0[0], 0, 0, 0);
    acc0[1] = __builtin_amdgcn_mfma_f32_16x16x32_bf16(ar0, b1, acc0[1], 0, 0, 0);
    acc0[2] = __builtin_amdgcn_mfma_f32_16x16x32_bf16(ar0, b2, acc0[2], 0, 0, 0);
    acc0[3] = __builtin_amdgcn_mfma_f32_16x16x32_bf16(ar0, b3, acc0[3], 0, 0, 0);
    acc1[0] = __builtin_amdgcn_mfma_f32_16x16x32_bf16(ar1, b0, acc1[0], 0, 0, 0);
    acc1[1] = __builtin_amdgcn_mfma_f32_16x16x32_bf16(ar1, b1, acc1[1], 0, 0, 0);
    acc1[2] = __builtin_amdgcn_mfma_f32_16x16x32_bf16(ar1, b2, acc1[2], 0, 0, 0);
    acc1[3] = __builtin_amdgcn_mfma_f32_16x16x32_bf16(ar1, b3, acc1[3], 0, 0, 0);
  }
  // C/D layout: col = lane&15, row = (lane>>4)*4 + reg
  float* ypb = yp + (size_t)(kp * 4 + w) * NROWS * 64;
  const int fr = l & 15, kg = l >> 4;
#pragma unroll
  for (int nf = 0; nf < 4; ++nf)
#pragma unroll
    for (int ri = 0; ri < 4; ++ri) {
      ypb[(size_t)(row0 + kg * 4 + ri) * 64 + nf * 16 + fr] = acc0[nf][ri];
      ypb[(size_t)(row0 + 16 + kg * 4 + ri) * 64 + nf * 16 + fr] = acc1[nf][ri];
    }
}

// ---------------- Kernel 4: combine partials, GNN layer + head, per-row losses ------
extern "C" __global__ void __launch_bounds__(256)
finish_kernel(const float* __restrict__ x2, const float* __restrict__ sqarr,
              const float* __restrict__ yp, const float* __restrict__ rs,
              const float* __restrict__ ss, const float* __restrict__ ws,
              const float* __restrict__ Wg, const float* __restrict__ bg,
              const float* __restrict__ W2, const float* __restrict__ b2,
              float* __restrict__ outp, float* __restrict__ l1c, float* __restrict__ l2c) {
  __shared__ float hbuf[4][64];
  __shared__ float gbuf[4][64];
  const int t = threadIdx.x;
  const int w = t >> 6, lane = t & 63;
  const int i = blockIdx.x * 4 + w;

  float yv = 0.f;
#pragma unroll
  for (int p = 0; p < 16; ++p)
    yv += yp[(size_t)p * NROWS * 64 + (size_t)i * 64 + lane];
  const float rowsum = rs[i], sumsq = ss[i], wsq = ws[i];
  const float inv = 1.0f / rowsum;
  hbuf[w][lane] = yv * inv;
  const float xv = x2[(size_t)i * 64 + lane];
  float xy = xv * yv;
#pragma unroll
  for (int off = 1; off < 64; off <<= 1) xy += __shfl_xor(xy, off);
  if (lane == 0) {
    l1c[i] = sqarr[i] + (wsq - (2.0f / 64.0f) * xy) * inv;
    l2c[i] = sumsq * inv * inv;
  }
  __syncthreads();
  float accg = bg[lane];
  {
    const float* wrow = Wg + lane * 64;
#pragma unroll 4
    for (int d = 0; d < 64; ++d) accg = fmaf(wrow[d], hbuf[w][d], accg);
  }
  gbuf[w][lane] = leaky_f(accg);
  __syncthreads();
  if (lane < 32) {
    float acco = b2[lane];
    const float* wrow = W2 + lane * 64;
#pragma unroll 4
    for (int d = 0; d < 64; ++d) acco = fmaf(wrow[d], gbuf[w][d], acco);
    outp[(size_t)i * 32 + lane] = acco;
  }
}

// ---------------- Kernel 5: scalar loss reduction -----------------------------------
extern "C" __global__ void __launch_bounds__(256)
loss_kernel(const float* __restrict__ l1c, const float* __restrict__ l2c,
            float* __restrict__ outp) {
  __shared__ float s1[256], s2[256];
  const int t = threadIdx.x;
  float a1 = 0.f, a2 = 0.f;
  for (int i = t * 4; i < NROWS; i += 1024) {
    const float4 v1 = *(const float4*)(l1c + i);
    const float4 v2 = *(const float4*)(l2c + i);
    a1 += (v1.x + v1.y) + (v1.z + v1.w);
    a2 += (v2.x + v2.y) + (v2.z + v2.w);
  }
  s1[t] = a1; s2[t] = a2;
  __syncthreads();
  for (int off = 128; off > 0; off >>= 1) {
    if (t < off) { s1[t] += s1[t + off]; s2[t] += s2[t + off]; }
    __syncthreads();
  }
  if (t == 0) {
    const float scale = 1.0f / ((float)NROWS * (float)NROWS);
    outp[NROWS * 32] = s1[0] * scale;
    outp[NROWS * 32 + 1] = s2[0] * scale;
  }
}

// ---------------- launch ------------------------------------------------------------
extern "C" void kernel_launch(void* const* d_in, const int* in_sizes, int n_in,
                              void* d_out, int out_size, void* d_ws, size_t ws_size,
                              hipStream_t stream) {
  const float* x   = (const float*)d_in[0];
  const float* A   = (const float*)d_in[1];
  const float* W10 = (const float*)d_in[2];
  const float* b10 = (const float*)d_in[3];
  const float* W11 = (const float*)d_in[4];
  const float* b11 = (const float*)d_in[5];
  const float* av  = (const float*)d_in[6];
  const float* Wg  = (const float*)d_in[7];
  const float* bg  = (const float*)d_in[8];
  const float* W2  = (const float*)d_in[9];
  const float* b2  = (const float*)d_in[10];
  float* out = (float*)d_out;

  // workspace layout (~175 MB)
  float* ws_f  = (float*)d_ws;
  float* x2    = ws_f;                                 // N*64
  float* sarr  = x2 + (size_t)NROWS * 64;              // N
  float* sqarr = sarr + NROWS;                         // N
  float* l1c   = sqarr + NROWS;                        // N
  float* l2c   = l1c + NROWS;                          // N
  float* rs    = l2c + NROWS;                          // N
  float* ssum  = rs + NROWS;                           // N
  float* wsq   = ssum + NROWS;                         // N
  float* rspc  = wsq + NROWS;                          // 262144
  float* sspc  = rspc + 262144;                        // 262144
  float* wspc  = sspc + 262144;                        // 262144
  float* yp    = wspc + 262144;                        // 16*N*64
  short* x2bfT = (short*)(yp + (size_t)16 * NROWS * 64);   // N*64
  short* Bfrag = x2bfT + (size_t)NROWS * 64;           // 256*2048
  short* raw   = Bfrag + (size_t)256 * 2048;           // N*N bf16 (128 MB)

  hipLaunchKernelGGL(encoder_kernel, dim3(2048), dim3(256), 0, stream,
                     x, W10, b10, W11, b11, av, x2, sarr, sqarr, x2bfT);
  hipLaunchKernelGGL(prep16_kernel, dim3(256), dim3(256), 0, stream, x2bfT, Bfrag);
  hipLaunchKernelGGL(convert_kernel, dim3(2048), dim3(256), 0, stream,
                     A, sarr, sqarr, raw, rspc, sspc, wspc);
  hipLaunchKernelGGL(rowreduce_kernel, dim3(32), dim3(256), 0, stream,
                     rspc, sspc, wspc, rs, ssum, wsq);
  hipLaunchKernelGGL(gemm_kernel, dim3(1024), dim3(256), 0, stream, raw, Bfrag, yp);
  hipLaunchKernelGGL(finish_kernel, dim3(2048), dim3(256), 0, stream,
                     x2, sqarr, yp, rs, ssum, wsq, Wg, bg, W2, b2, out, l1c, l2c);
  hipLaunchKernelGGL(loss_kernel, dim3(1), dim3(256), 0, stream, l1c, l2c, out);
}